// Round 3
// baseline (320.711 us; speedup 1.0000x reference)
//
#include <hip/hip_runtime.h>

typedef _Float16 f16;
typedef _Float16 f16x8 __attribute__((ext_vector_type(8)));
typedef float f32x4 __attribute__((ext_vector_type(4)));

#define OSTRIDE 1032   // halves: 1024 + 8 pad; o-stride = 2064 B (16 B aligned)

// Grid: (16 pair-slots, 225 (dx,dy) groups). Block = 512 thr = 8 waves,
// handles 4 (x,y,X,Y) pairs sharing one W[dx,dy] block (staged once, fp32->f16
// fused). Wave w: pair p0+(w>>1), b-tiles (w&1)*4..+3 (4 b-tiles per wave ->
// 4 MFMA per ds_read_b128 of the B-fragment).
__global__ __launch_bounds__(512, 4) void rel_mfma_one(
    const float* __restrict__ inp,   // (128,8,8,32)
    const float* __restrict__ W,     // (15,15,16,32,32) [dx][dy][o][i][j]
    const float* __restrict__ bias,  // (15,15,16)
    float* __restrict__ out)         // (128,8,8,8,8,16)
{
    __shared__ __align__(16) f16 Wl[16 * OSTRIDE];   // 33,024 B -> [o][i*32+j] padded

    const int dxdy = blockIdx.y;
    const int dx = dxdy / 15, dy = dxdy % 15;
    const int cx = 8 - abs(dx - 7), cy = 8 - abs(dy - 7);
    const int npairs = cx * cy;
    const int p0 = blockIdx.x * 4;
    if (p0 >= npairs) return;                        // block-uniform early exit

    const int t = threadIdx.x;
    const int lane = t & 63;
    const int wave = t >> 6;           // 0..7
    const int pair_sel = wave >> 1;    // 0..3
    const int whalf = wave & 1;        // b-tiles whalf*4 .. +3
    const int quad = lane >> 4;
    const int m = lane & 15;           // A-row (b%16) and B-col (o)

    // ---- this wave's pair -> (x,y,X,Y) ----
    const bool valid = (p0 + pair_sel) < npairs;
    const int p = valid ? (p0 + pair_sel) : 0;
    const int ix = p / cy, iy = p - ix * cy;
    const int x = (dx < 7 ? 7 - dx : 0) + ix;
    const int y = (dy < 7 ? 7 - dy : 0) + iy;
    const int X = x + dx - 7;
    const int Y = y + dy - 7;

    // ---- preload a-rows + c-frags (fp32 -> f16), latency hidden under staging ----
    f16x8 a[4][4];   // [tile][i-chunk of 8]
    f16x8 c[4];      // [tile] : c[b, quad*8 .. +7]
    #pragma unroll
    for (int tt = 0; tt < 4; ++tt) {
        const int b = (whalf * 4 + tt) * 16 + m;
        const float* ar = inp + ((b * 8 + x) * 8 + y) * 32;
        const float* cr = inp + ((b * 8 + X) * 8 + Y) * 32 + quad * 8;
        #pragma unroll
        for (int g = 0; g < 4; ++g) {
            const float4 v0 = *(const float4*)(ar + g * 8);
            const float4 v1 = *(const float4*)(ar + g * 8 + 4);
            a[tt][g] = f16x8{ (f16)v0.x, (f16)v0.y, (f16)v0.z, (f16)v0.w,
                              (f16)v1.x, (f16)v1.y, (f16)v1.z, (f16)v1.w };
        }
        const float4 w0 = *(const float4*)(cr);
        const float4 w1 = *(const float4*)(cr + 4);
        c[tt] = f16x8{ (f16)w0.x, (f16)w0.y, (f16)w0.z, (f16)w0.w,
                       (f16)w1.x, (f16)w1.y, (f16)w1.z, (f16)w1.w };
    }

    // ---- stage W[dx,dy] fp32 -> f16 LDS, coalesced (2 KB/wave-instr) ----
    {
        const float* Wg = W + (size_t)dxdy * 16384;
        #pragma unroll
        for (int it = 0; it < 4; ++it) {
            const int e = (it * 512 + t) * 8;        // 8-elem granule
            const int o = e >> 10, within = e & 1023;
            const float4 v0 = *(const float4*)(Wg + e);
            const float4 v1 = *(const float4*)(Wg + e + 4);
            f16x8 h = { (f16)v0.x, (f16)v0.y, (f16)v0.z, (f16)v0.w,
                        (f16)v1.x, (f16)v1.y, (f16)v1.z, (f16)v1.w };
            *(f16x8*)(&Wl[o * OSTRIDE + within]) = h;
        }
    }
    __syncthreads();

    // ---- K-loop: 32 steps (i), bfrag shared by 4 b-tiles ----
    f32x4 acc[4] = { {0,0,0,0}, {0,0,0,0}, {0,0,0,0}, {0,0,0,0} };
    const f16* wl = &Wl[m * OSTRIDE + quad * 8];
    #pragma unroll
    for (int g = 0; g < 4; ++g) {
        #pragma unroll
        for (int u = 0; u < 8; ++u) {
            const int kb = g * 8 + u;                       // = i
            const f16x8 bfrag = *(const f16x8*)(wl + kb * 32); // W[o=m, kb, quad*8+r]
            #pragma unroll
            for (int tt = 0; tt < 4; ++tt) {
                const f16x8 af = c[tt] * a[tt][g][u];       // P[b, kb*32+quad*8+r]
                acc[tt] = __builtin_amdgcn_mfma_f32_16x16x32_f16(af, bfrag, acc[tt], 0, 0, 0);
            }
        }
    }

    // ---- epilogue: D[row=b%16=quad*4+r, col=o=m]; bias[dx,dy,o] ----
    if (valid) {
        const float bv = bias[dxdy * 16 + m];
        const size_t pos = (size_t)((x * 8 + y) * 64 + (X * 8 + Y)) * 16 + m;
        #pragma unroll
        for (int tt = 0; tt < 4; ++tt) {
            #pragma unroll
            for (int r = 0; r < 4; ++r) {
                const int b = (whalf * 4 + tt) * 16 + quad * 4 + r;
                out[(size_t)b * 65536 + pos] = acc[tt][r] + bv;
            }
        }
    }
}

extern "C" void kernel_launch(void* const* d_in, const int* in_sizes, int n_in,
                              void* d_out, int out_size, void* d_ws, size_t ws_size,
                              hipStream_t stream)
{
    const float* inp  = (const float*)d_in[0];
    const float* W    = (const float*)d_in[1];
    const float* bias = (const float*)d_in[2];
    float* out = (float*)d_out;

    dim3 grid(16, 225);   // pair-slots x (dx,dy); empty slots exit immediately
    dim3 block(512);
    hipLaunchKernelGGL(rel_mfma_one, grid, block, 0, stream, inp, W, bias, out);
}

// Round 4
// 105.942 us; speedup vs baseline: 3.0272x; 3.0272x over previous
//
#include <hip/hip_runtime.h>

typedef _Float16 f16;
typedef _Float16 f16x8 __attribute__((ext_vector_type(8)));
typedef float f32x4 __attribute__((ext_vector_type(4)));
typedef unsigned int u32;
typedef const __attribute__((address_space(1))) u32* gas1_t;
typedef __attribute__((address_space(3))) u32* las3_t;

#define WGRAN 460800   // 225 * 2048 granules of 8 halves (W)
#define IGRAN 32768    // 262144/8 granules (inp)

// fp32 -> f16 with W permuted into the LDS-ready layout:
// W_h[dxdy][i][o][quad] (granules of 8 halves) = W[dxdy][o][i][quad*8+u]
__global__ __launch_bounds__(256) void convert_kernel(
    const float* __restrict__ W, const float* __restrict__ inp,
    f16* __restrict__ W_h, f16* __restrict__ inp_h)
{
    const int g = blockIdx.x * 256 + threadIdx.x;   // grid sized exactly
    if (g < WGRAN) {
        const int dxdy = g >> 11;
        const int r = g & 2047;
        const int i = r >> 6, o = (r >> 2) & 15, quad = r & 3;
        const float* src = W + (size_t)dxdy * 16384 + o * 1024 + i * 32 + quad * 8;
        const float4 v0 = *(const float4*)src;
        const float4 v1 = *(const float4*)(src + 4);
        f16x8 h = { (f16)v0.x, (f16)v0.y, (f16)v0.z, (f16)v0.w,
                    (f16)v1.x, (f16)v1.y, (f16)v1.z, (f16)v1.w };
        *(f16x8*)(W_h + (size_t)g * 8) = h;
    } else {
        const int k = g - WGRAN;
        const float* src = inp + (size_t)k * 8;
        const float4 v0 = *(const float4*)src;
        const float4 v1 = *(const float4*)(src + 4);
        f16x8 h = { (f16)v0.x, (f16)v0.y, (f16)v0.z, (f16)v0.w,
                    (f16)v1.x, (f16)v1.y, (f16)v1.z, (f16)v1.w };
        *(f16x8*)(inp_h + (size_t)k * 8) = h;
    }
}

// One block per (x,y,X,Y). LDS layout [i][o][quad] (8-half granules):
// bfrag addr (halves) = i*512 + o*32 + quad*8 -> conflict-free ds_read_b128
// (start banks = (16*(o&1) + 4*quad), all 32 banks covered per 8-lane phase).
__global__ __launch_bounds__(256, 5) void rel_mfma2(
    const f16* __restrict__ W_h,    // [dxdy][i][o][quad][8]
    const f16* __restrict__ inp_h,  // (128,8,8,32)
    const float* __restrict__ bias, // (15,15,16)
    float* __restrict__ out)        // (128,8,8,8,8,16)
{
    __shared__ __align__(16) f16 Wl[16384];   // 32 KB -> 5 blocks/CU

    const int bid = blockIdx.x;
    const int Y = bid & 7, X = (bid >> 3) & 7, y = (bid >> 6) & 7, x = (bid >> 9) & 7;
    const int dx = X - x + 7, dy = Y - y + 7;
    const int dxdy = dx * 15 + dy;

    const int t = threadIdx.x;

    // ---- stage W-block: straight copy, global_load_lds width=16 ----
    {
        const f16* base = W_h + (size_t)dxdy * 16384;
        #pragma unroll
        for (int it = 0; it < 8; ++it) {
            const int idx = (it * 256 + t) * 8;          // 8-half granule, 16 B
            __builtin_amdgcn_global_load_lds((gas1_t)(base + idx),
                                             (las3_t)&Wl[idx], 16, 0, 0);
        }
    }

    const int lane = t & 63;
    const int wave = t >> 6;       // 0..3 -> b-tiles 2w, 2w+1
    const int quad = lane >> 4;
    const int m = lane & 15;       // A-row (b%16) and B-col (o)

    // ---- a-rows + c-frags from f16 inp (independent of LDS DMA) ----
    f16x8 a0[4], a1[4], c0, c1;
    {
        const int b0 = wave * 32 + m;
        const int b1 = b0 + 16;
        const f16* ar0 = inp_h + ((b0 * 8 + x) * 8 + y) * 32;
        const f16* ar1 = inp_h + ((b1 * 8 + x) * 8 + y) * 32;
        #pragma unroll
        for (int g = 0; g < 4; ++g) {
            a0[g] = *(const f16x8*)(ar0 + g * 8);
            a1[g] = *(const f16x8*)(ar1 + g * 8);
        }
        c0 = *(const f16x8*)(inp_h + ((b0 * 8 + X) * 8 + Y) * 32 + quad * 8);
        c1 = *(const f16x8*)(inp_h + ((b1 * 8 + X) * 8 + Y) * 32 + quad * 8);
    }

    __syncthreads();   // drains vmcnt -> LDS DMA complete

    // ---- K-loop: 32 steps (i = kb); bfrag shared by both b-tiles ----
    f32x4 acc0 = {0.f, 0.f, 0.f, 0.f};
    f32x4 acc1 = {0.f, 0.f, 0.f, 0.f};
    const f16* wl = &Wl[m * 32 + quad * 8];
    #pragma unroll
    for (int g = 0; g < 4; ++g) {
        #pragma unroll
        for (int u = 0; u < 8; ++u) {
            const int kb = g * 8 + u;
            const f16x8 bfrag = *(const f16x8*)(wl + kb * 512); // W[o=m, kb, quad*8+r]
            const f16x8 af0 = c0 * a0[g][u];    // P[b, kb*32 + quad*8 + r]
            const f16x8 af1 = c1 * a1[g][u];
            acc0 = __builtin_amdgcn_mfma_f32_16x16x32_f16(af0, bfrag, acc0, 0, 0, 0);
            acc1 = __builtin_amdgcn_mfma_f32_16x16x32_f16(af1, bfrag, acc1, 0, 0, 0);
        }
    }

    // ---- epilogue: D[row=b%16=quad*4+r, col=o=m] ----
    const float bv = bias[dxdy * 16 + m];
    #pragma unroll
    for (int r = 0; r < 4; ++r) {
        const int b0 = wave * 32 + quad * 4 + r;
        const int b1 = b0 + 16;
        out[((size_t)b0 * 4096 + bid) * 16 + m] = acc0[r] + bv;
        out[((size_t)b1 * 4096 + bid) * 16 + m] = acc1[r] + bv;
    }
}

extern "C" void kernel_launch(void* const* d_in, const int* in_sizes, int n_in,
                              void* d_out, int out_size, void* d_ws, size_t ws_size,
                              hipStream_t stream)
{
    const float* inp  = (const float*)d_in[0];  // (128,8,8,32)
    const float* W    = (const float*)d_in[1];  // (15,15,16,32,32)
    const float* bias = (const float*)d_in[2];  // (15,15,16)
    float* out = (float*)d_out;

    f16* W_h   = (f16*)d_ws;                         // 7,372,800 halves
    f16* inp_h = (f16*)d_ws + (size_t)WGRAN * 8;     //   262,144 halves

    hipLaunchKernelGGL(convert_kernel, dim3((WGRAN + IGRAN) / 256), dim3(256), 0,
                       stream, W, inp, W_h, inp_h);
    hipLaunchKernelGGL(rel_mfma2, dim3(4096), dim3(256), 0, stream,
                       W_h, inp_h, bias, out);
}